// Round 3
// baseline (1301.491 us; speedup 1.0000x reference)
//
#include <hip/hip_runtime.h>
#include <hip/hip_bf16.h>
#include <hip/hip_cooperative_groups.h>
#include <cstddef>

namespace cg = cooperative_groups;

// Problem constants (fixed by the reference)
constexpr int T_ = 512;
constexpr int B_ = 8;
constexpr int H_ = 256;
constexpr int V_ = 32000;
constexpr int L_ = 3;
constexpr int M_ = T_ * B_;   // 4096 rows in all GEMMs

typedef __attribute__((ext_vector_type(8))) short short8;
typedef __attribute__((ext_vector_type(4))) float floatx4;

// fp32 -> bf16 round-to-nearest-even
__device__ __forceinline__ unsigned short f2bf(float f) {
    unsigned u = __float_as_uint(f);
    u += 0x7fffu + ((u >> 16) & 1u);
    return (unsigned short)(u >> 16);
}

// async global->LDS, 16B per lane; LDS dest = wave-uniform base + lane*16
__device__ __forceinline__ void gl_lds16(const void* g, void* l) {
    __builtin_amdgcn_global_load_lds((__attribute__((address_space(1))) void*)g,
                                     (__attribute__((address_space(3))) void*)l,
                                     16, 0, 0);
}

// ---------------------------------------------------------------------------
// Merged weight transpose+cast (one dispatch):
//   blocks 0..95   : 6x [256][256] fp32 (k-major) -> [256][256] bf16  (WT)
//   blocks 96..2095: Wout [256][32000] fp32 -> WoutT [32000][256] bf16
// ---------------------------------------------------------------------------
__global__ __launch_bounds__(256) void transpose_all_kernel(
    const float* __restrict__ Wq, const float* __restrict__ Wfc,
    const float* __restrict__ Wout,
    unsigned short* __restrict__ WT, unsigned short* __restrict__ WoutT)
{
    __shared__ float t[64][65];
    const int bx = blockIdx.x;
    const float* src; unsigned short* dst;
    int n0, k0, sstride;
    if (bx < 96) {                       // small: z = bx>>4, 4x4 tiles of 64
        const int z = bx >> 4, r = bx & 15;
        src = (z < 3) ? Wq + (size_t)z * H_ * H_
                      : Wfc + (size_t)(z - 3) * H_ * H_;
        dst = WT + (size_t)z * H_ * H_;
        n0 = (r & 3) * 64; k0 = (r >> 2) * 64;
        sstride = H_;
    } else {                             // Wout: (V/64=500) x (H/64=4)
        const int nb = bx - 96;
        src = Wout; dst = WoutT;
        n0 = (nb >> 2) * 64; k0 = (nb & 3) * 64;
        sstride = V_;
    }
    const int x = threadIdx.x & 63, y = threadIdx.x >> 6;
    #pragma unroll
    for (int i = 0; i < 16; ++i)
        t[y + 4 * i][x] = src[(size_t)(k0 + y + 4 * i) * sstride + n0 + x];
    __syncthreads();
    #pragma unroll
    for (int i = 0; i < 16; ++i)
        dst[(size_t)(n0 + y + 4 * i) * H_ + k0 + x] = f2bf(t[x][y + 4 * i]);
}

// ===========================================================================
// XOR-swizzled LDS staging (all MFMA GEMMs): chunk = 16 B = 8 bf16 k-octet.
//   BK=64 tiles: slot = row*8 + (oct ^ (row & 7))        (layer GEMM)
//   BK=32 tiles: slot = row*4 + (oct ^ ((row>>1) & 3))   (out GEMM)
// Both keep fragment ds_read_b128 at 2-way bank aliasing (free per m136);
// global_load_lds groups of 64 slots stay line-coalesced.
// ===========================================================================

constexpr int CH_ = 32;
constexpr int NT_ = T_ / CH_;          // 16 chunks
constexpr int TS_ = B_ * H_;           // 2048: t-stride in [T][B][H]

// ---------------------------------------------------------------------------
// Device phase: 64x64 layer GEMM tile (BK=64, 4 waves 2x2 over 32m x 32n).
// bx in [0,256): m0 = (bx>>2)*64, n0 = (bx&3)*64. Identical math/order to the
// R6 standalone gemm_mfma_layer (bitwise-same outputs).
// ---------------------------------------------------------------------------
template <int RELU, int OUT_BF16>
__device__ __forceinline__ void gemm_layer_phase(
    const unsigned short* __restrict__ A, const unsigned short* __restrict__ Bt,
    const float* __restrict__ bias, float* __restrict__ Cf,
    unsigned short* __restrict__ Cb, short (*lA)[8], short (*lB)[8],
    int bx, int tid)
{
    constexpr int K = H_, N = H_;
    const int lane = tid & 63, wave = tid >> 6;
    const int wm = wave >> 1, wn = wave & 1;
    const int l15 = lane & 15, quad = lane >> 4;
    const int m0 = (bx >> 2) * 64;
    const int n0 = (bx & 3) * 64;

    floatx4 acc[2][2] = {};

    for (int k0 = 0; k0 < K; k0 += 64) {
        #pragma unroll
        for (int j = 0; j < 2; ++j) {
            const int base = (wave * 2 + j) * 64;
            const int s = base + lane;
            const int row = s >> 3;
            const int oct = (s & 7) ^ (row & 7);
            gl_lds16(A + (size_t)(m0 + row) * K + k0 + oct * 8, &lA[base][0]);
        }
        #pragma unroll
        for (int j = 0; j < 2; ++j) {
            const int base = (wave * 2 + j) * 64;
            const int s = base + lane;
            const int row = s >> 3;
            const int oct = (s & 7) ^ (row & 7);
            gl_lds16(Bt + (size_t)(n0 + row) * K + k0 + oct * 8, &lB[base][0]);
        }
        __syncthreads();

        #pragma unroll
        for (int t = 0; t < 2; ++t) {
            short8 af[2], bf[2];
            #pragma unroll
            for (int f = 0; f < 2; ++f) {
                const int ra = wm * 32 + f * 16 + l15;
                af[f] = *(const short8*)&lA[ra * 8 + ((4 * t + quad) ^ (ra & 7))][0];
            }
            #pragma unroll
            for (int g = 0; g < 2; ++g) {
                const int rb = wn * 32 + g * 16 + l15;
                bf[g] = *(const short8*)&lB[rb * 8 + ((4 * t + quad) ^ (rb & 7))][0];
            }
            #pragma unroll
            for (int f = 0; f < 2; ++f)
                #pragma unroll
                for (int g = 0; g < 2; ++g)
                    acc[f][g] = __builtin_amdgcn_mfma_f32_16x16x32_bf16(
                        af[f], bf[g], acc[f][g], 0, 0, 0);
        }
        __syncthreads();
    }

    #pragma unroll
    for (int g = 0; g < 2; ++g) {
        const int col = n0 + wn * 32 + g * 16 + l15;
        const float bv = bias[col];
        #pragma unroll
        for (int f = 0; f < 2; ++f) {
            const int rbase = m0 + wm * 32 + f * 16 + quad * 4;
            #pragma unroll
            for (int r = 0; r < 4; ++r) {
                float v = acc[f][g][r] + bv;
                if (RELU) v = fmaxf(v, 0.0f);
                if (OUT_BF16)
                    Cb[(size_t)(rbase + r) * N + col] = f2bf(v);
                else
                    Cf[(size_t)(rbase + r) * N + col] = v;
            }
        }
    }
}

// ===========================================================================
// Cooperative fused kernel: embed + 3 x (qproj -> chunked scan -> fc).
// Grid = 256 blocks x 256 threads (1 block/CU, 17 KB LDS -> trivially
// co-resident). Replaces 11 tiny launch/ramp/drain-bound kernels with one
// launch + 12 grid syncs. Scan numerics = the R5/R6-proven chunked
// local+carry scheme (absmax 0.0 there).
// ===========================================================================
__global__ __launch_bounds__(256) void fused_layers_coop(
    const int* __restrict__ tokens, const float* __restrict__ temb,
    const float* __restrict__ pemb, const unsigned short* __restrict__ WT,
    const float* __restrict__ bq, const float* __restrict__ beta,
    const float* __restrict__ bfc, unsigned short* __restrict__ h_bf,
    unsigned short* __restrict__ spk, float* __restrict__ cur,
    float* __restrict__ mloc)
{
    __shared__ __align__(16) short lA[512][8];   // 8 KiB
    __shared__ __align__(16) short lB[512][8];   // 8 KiB

    cg::grid_group grid = cg::this_grid();
    const int bx = blockIdx.x, tid = threadIdx.x;

    // ---- phase 0: embed (1024 block-units of work over 256 blocks) ----
    #pragma unroll
    for (int i = 0; i < 4; ++i) {
        const int idx = (bx + 256 * i) * 256 + tid;   // 0 .. M*H/4-1
        const int h4 = idx & (H_ / 4 - 1);
        const int tb = idx >> 6;
        const int b  = tb & (B_ - 1);
        const int t  = tb >> 3;
        const int tok = tokens[t * B_ + b];
        const float4 e = *(const float4*)&temb[(size_t)tok * H_ + h4 * 4];
        const float4 p = *(const float4*)&pemb[(size_t)t * H_ + h4 * 4];
        ushort4 r;
        r.x = f2bf(e.x + p.x); r.y = f2bf(e.y + p.y);
        r.z = f2bf(e.z + p.z); r.w = f2bf(e.w + p.w);
        *(ushort4*)&h_bf[(size_t)idx * 4] = r;
    }
    __threadfence();
    grid.sync();

    for (int l = 0; l < L_; ++l) {
        const unsigned short* WqT  = WT + (size_t)l * H_ * H_;
        const unsigned short* WfcT = WT + (size_t)(L_ + l) * H_ * H_;
        const float* beta_l = beta + (size_t)l * H_;

        // ---- qproj: cur = h_bf @ WqT^T + bq (fp32) ----
        gemm_layer_phase<0, 0>(h_bf, WqT, bq + (size_t)l * H_, cur, nullptr,
                               lA, lB, bx, tid);
        __threadfence();
        grid.sync();

        // ---- scan_local: per-chunk recurrence (blocks 0..127) ----
        if (bx < 128) {
            const int c = bx & 15, b = bx >> 4, h = tid;
            const float bt = beta_l[h];
            const size_t off = ((size_t)(c * CH_) * B_ + b) * H_ + h;
            const float* p = cur + off;
            float* q = mloc + off;
            float mem = 0.0f;
            #pragma unroll
            for (int tt = 0; tt < CH_; ++tt) {
                mem = fmaf(bt, mem, p[(size_t)tt * TS_]);
                q[(size_t)tt * TS_] = mem;
            }
        }
        __threadfence();
        grid.sync();

        // ---- scan_apply: carry across chunks + spike (blocks 0..127) ----
        if (bx < 128) {
            const int c = bx & 15, b = bx >> 4, h = tid;
            const float bt = beta_l[h];
            float b32 = bt;
            #pragma unroll
            for (int i = 0; i < 5; ++i) b32 *= b32;        // beta^32
            float carry = 0.0f;
            for (int j = 0; j < c; ++j)
                carry = fmaf(b32, carry,
                             mloc[((size_t)(j * CH_ + CH_ - 1) * B_ + b) * H_ + h]);
            const size_t off = ((size_t)(c * CH_) * B_ + b) * H_ + h;
            const float* p = mloc + off;
            unsigned short* q = spk + off;
            float pw = bt;                                  // beta^(tt+1)
            #pragma unroll
            for (int tt = 0; tt < CH_; ++tt) {
                const float mem = fmaf(pw, carry, p[(size_t)tt * TS_]);
                pw *= bt;
                q[(size_t)tt * TS_] = (mem > 1.0f) ? (unsigned short)0x3F80u
                                                   : (unsigned short)0u;
            }
        }
        __threadfence();
        grid.sync();

        // ---- fc: h_bf = relu(spk @ WfcT^T + bfc) (bf16) ----
        gemm_layer_phase<1, 1>(spk, WfcT, bfc + (size_t)l * H_, nullptr, h_bf,
                               lA, lB, bx, tid);
        if (l < L_ - 1) {
            __threadfence();
            grid.sync();
        }
    }
}

// ---------------------------------------------------------------------------
// Final projection: C[M,V] = A[M,256]bf16 @ WoutT[V,256]^T + bias, fp32 out.
// BK=32 double-buffered 2-phase K-pipeline; epilogue = per-wave LDS scratch
// -> full-line (4 rows x 256 B) NON-TEMPORAL stores. R7 proved NT is
// load-bearing: plain stores through L2 cost +130-150 us on the 524 MB
// C stream. Do not remove NT.
// ---------------------------------------------------------------------------
__global__ __launch_bounds__(256, 2) void gemm_mfma_out(
    const unsigned short* __restrict__ A,    // [M][256] bf16
    const unsigned short* __restrict__ Bt,   // [V][256] bf16
    const float* __restrict__ bias,          // [V]
    float* __restrict__ C)
{
    constexpr int K = H_, N = V_;
    __shared__ __align__(16) short lA[2][1024][8];  // 2 x 16 KiB
    __shared__ __align__(16) short lB[2][512][8];   // 2 x  8 KiB

    const int tid = threadIdx.x;
    const int lane = tid & 63, wave = tid >> 6;
    const int wm = wave >> 1, wn = wave & 1;     // wave-tile: 128m x 64n
    const int l15 = lane & 15, quad = lane >> 4;
    const int m0 = blockIdx.x * 256;             // x = m (fast)
    const int n0 = blockIdx.y * 128;

    floatx4 acc[8][4] = {};

    auto stage = [&](int buf, int ks) {
        const int k0 = ks * 32;
        #pragma unroll
        for (int j = 0; j < 4; ++j) {            // A: 1024 slots
            const int base = (wave * 4 + j) * 64;
            const int s = base + lane;
            const int row = s >> 2;
            const int oct = (s & 3) ^ ((row >> 1) & 3);
            gl_lds16(A + (size_t)(m0 + row) * K + k0 + oct * 8, &lA[buf][base][0]);
        }
        #pragma unroll
        for (int j = 0; j < 2; ++j) {            // B: 512 slots
            const int base = (wave * 2 + j) * 64;
            const int s = base + lane;
            const int row = s >> 2;
            const int oct = (s & 3) ^ ((row >> 1) & 3);
            gl_lds16(Bt + (size_t)(n0 + row) * K + k0 + oct * 8, &lB[buf][base][0]);
        }
    };

    stage(0, 0);
    __syncthreads();                              // buf0 staged (full drain)

    for (int ks = 0; ks < 8; ++ks) {
        const int cur = ks & 1;
        if (ks < 7) stage(cur ^ 1, ks + 1);       // prefetch next slice first
        short8 af[8], bf[4];
        #pragma unroll
        for (int f = 0; f < 8; ++f) {
            const int ra = wm * 128 + f * 16 + l15;
            af[f] = *(const short8*)&lA[cur][ra * 4 + (quad ^ ((ra >> 1) & 3))][0];
        }
        #pragma unroll
        for (int g = 0; g < 4; ++g) {
            const int rb = wn * 64 + g * 16 + l15;
            bf[g] = *(const short8*)&lB[cur][rb * 4 + (quad ^ ((rb >> 1) & 3))][0];
        }
        #pragma unroll
        for (int f = 0; f < 8; ++f)
            #pragma unroll
            for (int g = 0; g < 4; ++g)
                acc[f][g] = __builtin_amdgcn_mfma_f32_16x16x32_bf16(
                    af[f], bf[g], acc[f][g], 0, 0, 0);
        __syncthreads();
    }

    // ---- epilogue via per-wave LDS scratch -> full-line NT stores ----
    // D layout per frag: col(n) = l15, row(m) = quad*4 + r (m89/m91-verified).
    float* scr = (float*)&lA[0][0][0] + (size_t)wave * 1088;   // 16 x 68 fp32
    float bvv[4];
    #pragma unroll
    for (int g = 0; g < 4; ++g)
        bvv[g] = bias[n0 + wn * 64 + g * 16 + l15];

    #pragma unroll
    for (int f = 0; f < 8; ++f) {
        #pragma unroll
        for (int g = 0; g < 4; ++g)
            #pragma unroll
            for (int r = 0; r < 4; ++r)
                scr[(quad * 4 + r) * 68 + g * 16 + l15] = acc[f][g][r] + bvv[g];
        asm volatile("s_waitcnt lgkmcnt(0)" ::: "memory");
        #pragma unroll
        for (int rr = 0; rr < 4; ++rr) {
            const int ml = rr * 4 + quad;
            const floatx4 v = *(const floatx4*)&scr[ml * 68 + l15 * 4];
            const size_t m = (size_t)(m0 + wm * 128 + f * 16 + ml);
            __builtin_nontemporal_store(
                v, (floatx4*)&C[m * (size_t)N + n0 + wn * 64 + l15 * 4]);
        }
        asm volatile("s_waitcnt lgkmcnt(0)" ::: "memory");  // reads landed
    }
}

// ---------------------------------------------------------------------------
extern "C" void kernel_launch(void* const* d_in, const int* in_sizes, int n_in,
                              void* d_out, int out_size, void* d_ws, size_t ws_size,
                              hipStream_t stream)
{
    const int*   tokens = (const int*)  d_in[0];
    const float* temb   = (const float*)d_in[1];
    const float* pemb   = (const float*)d_in[2];
    const float* Wq     = (const float*)d_in[3];
    const float* bq     = (const float*)d_in[4];
    const float* beta   = (const float*)d_in[5];
    const float* Wfc    = (const float*)d_in[6];
    const float* bfc    = (const float*)d_in[7];
    const float* Wout   = (const float*)d_in[8];
    const float* bout   = (const float*)d_in[9];
    float* out = (float*)d_out;

    // Workspace layout (all 16B-aligned): h_bf 2MB | spk 2MB | WT 0.75MB |
    // WoutT 16MB | cur 4MB | mloc 4MB
    unsigned short* h_bf  = (unsigned short*)d_ws;
    unsigned short* spk   = h_bf + (size_t)M_ * H_;
    unsigned short* WT    = spk + (size_t)M_ * H_;          // 6 x [256][256]
    unsigned short* WoutT = WT + (size_t)2 * L_ * H_ * H_;
    float*          cur   = (float*)(WoutT + (size_t)V_ * H_);
    float*          mloc  = cur + (size_t)M_ * H_;

    // Weight transposes (independent of activation pipeline) — one dispatch
    transpose_all_kernel<<<96 + (V_ / 64) * (H_ / 64), 256, 0, stream>>>(
        Wq, Wfc, Wout, WT, WoutT);

    // embed + all 3 layers in ONE cooperative launch (replaces 11 launches)
    const unsigned short* WTc = WT;
    void* args[] = {
        (void*)&tokens, (void*)&temb, (void*)&pemb, (void*)&WTc,
        (void*)&bq, (void*)&beta, (void*)&bfc,
        (void*)&h_bf, (void*)&spk, (void*)&cur, (void*)&mloc
    };
    hipLaunchCooperativeKernel((const void*)fused_layers_coop,
                               dim3(256), dim3(256), args, 0, stream);

    // output projection: (4096 x 256) @ (256 x 32000) + bout
    gemm_mfma_out<<<dim3(M_ / 256, V_ / 128), 256, 0, stream>>>(
        h_bf, WoutT, bout, out);
}

// Round 4
// 717.592 us; speedup vs baseline: 1.8137x; 1.8137x over previous
//
#include <hip/hip_runtime.h>
#include <hip/hip_bf16.h>
#include <cstddef>

// Problem constants (fixed by the reference)
constexpr int T_ = 512;
constexpr int B_ = 8;
constexpr int H_ = 256;
constexpr int V_ = 32000;
constexpr int L_ = 3;
constexpr int M_ = T_ * B_;   // 4096 rows in all GEMMs

typedef __attribute__((ext_vector_type(8))) short short8;
typedef __attribute__((ext_vector_type(4))) float floatx4;

// fp32 -> bf16 round-to-nearest-even
__device__ __forceinline__ unsigned short f2bf(float f) {
    unsigned u = __float_as_uint(f);
    u += 0x7fffu + ((u >> 16) & 1u);
    return (unsigned short)(u >> 16);
}

// async global->LDS, 16B per lane; LDS dest = wave-uniform base + lane*16
__device__ __forceinline__ void gl_lds16(const void* g, void* l) {
    __builtin_amdgcn_global_load_lds((__attribute__((address_space(1))) void*)g,
                                     (__attribute__((address_space(3))) void*)l,
                                     16, 0, 0);
}

// ---------------------------------------------------------------------------
// Embed: h_bf[t,b,:] = bf16(token_emb[tokens[t,b],:] + pos_emb[t,:])
// ---------------------------------------------------------------------------
__global__ __launch_bounds__(256) void embed_kernel(
    const int* __restrict__ tokens, const float* __restrict__ temb,
    const float* __restrict__ pemb, unsigned short* __restrict__ hb)
{
    const int idx = blockIdx.x * 256 + threadIdx.x;      // 0 .. T*B*H/4-1
    const int h4 = idx & (H_ / 4 - 1);
    const int tb = idx >> 6;
    const int b  = tb & (B_ - 1);
    const int t  = tb >> 3;
    const int tok = tokens[t * B_ + b];
    const float4 e = *(const float4*)&temb[(size_t)tok * H_ + h4 * 4];
    const float4 p = *(const float4*)&pemb[(size_t)t * H_ + h4 * 4];
    ushort4 r;
    r.x = f2bf(e.x + p.x); r.y = f2bf(e.y + p.y);
    r.z = f2bf(e.z + p.z); r.w = f2bf(e.w + p.w);
    *(ushort4*)&hb[(size_t)idx * 4] = r;
}

// ---------------------------------------------------------------------------
// Merged weight transpose+cast (one dispatch):
//   blocks 0..95   : 6x [256][256] fp32 (k-major) -> [256][256] bf16  (WT)
//   blocks 96..2095: Wout [256][32000] fp32 -> WoutT [32000][256] bf16
// ---------------------------------------------------------------------------
__global__ __launch_bounds__(256) void transpose_all_kernel(
    const float* __restrict__ Wq, const float* __restrict__ Wfc,
    const float* __restrict__ Wout,
    unsigned short* __restrict__ WT, unsigned short* __restrict__ WoutT)
{
    __shared__ float t[64][65];
    const int bx = blockIdx.x;
    const float* src; unsigned short* dst;
    int n0, k0, sstride;
    if (bx < 96) {                       // small: z = bx>>4, 4x4 tiles of 64
        const int z = bx >> 4, r = bx & 15;
        src = (z < 3) ? Wq + (size_t)z * H_ * H_
                      : Wfc + (size_t)(z - 3) * H_ * H_;
        dst = WT + (size_t)z * H_ * H_;
        n0 = (r & 3) * 64; k0 = (r >> 2) * 64;
        sstride = H_;
    } else {                             // Wout: (V/64=500) x (H/64=4)
        const int nb = bx - 96;
        src = Wout; dst = WoutT;
        n0 = (nb >> 2) * 64; k0 = (nb & 3) * 64;
        sstride = V_;
    }
    const int x = threadIdx.x & 63, y = threadIdx.x >> 6;
    #pragma unroll
    for (int i = 0; i < 16; ++i)
        t[y + 4 * i][x] = src[(size_t)(k0 + y + 4 * i) * sstride + n0 + x];
    __syncthreads();
    #pragma unroll
    for (int i = 0; i < 16; ++i)
        dst[(size_t)(n0 + y + 4 * i) * H_ + k0 + x] = f2bf(t[x][y + 4 * i]);
}

// ===========================================================================
// XOR-swizzled LDS staging (all MFMA GEMMs): chunk = 16 B = 8 bf16 k-octet.
// Within each 64-k subtile: slot = row*8 + (oct ^ (row & 7)); 16B slots.
// Fragment ds_read_b128 stays at free 2-way bank aliasing (m136); gl_lds
// groups of 64 slots stay line-coalesced.
// R8 lesson: grid.sync() costs ~55-60us each on MI355X -> NO cooperative
// fusion. Instead: per-layer fusion with intra-block deps only (below).
// ===========================================================================

constexpr int CH_ = 32;               // scan chunk (proven CH=32 numerics)
constexpr int NT_ = T_ / CH_;         // 16 chunks

// ---------------------------------------------------------------------------
// Fused qproj + chunk-local scan.  Grid (16 chunks, 4 h-slices), 512 thr.
// Block tile: 256 m-rows (= chunk c: m = c*256..c*256+255) x 64 n-cols
// (n = hidden dim slice). 8 waves 4x2 over (64m x 32n). K=256 staged as
// B full-K (32KB) + A in two 128-k halves (64KB each, reused buffer).
// MFMA k-order = ascending 32-k steps (bitwise-identical to R6 path).
// Epilogue: acc+bias -> LDS f32 scratch -> chunk-local scan (mem = fmaf(
// beta, mem, cur)) -> mloc.  `cur` never touches global memory.
// ---------------------------------------------------------------------------
__global__ __launch_bounds__(512, 1) void qproj_scan_kernel(
    const unsigned short* __restrict__ A,    // h_bf [M][256] bf16
    const unsigned short* __restrict__ Bt,   // WqT [256][256] bf16
    const float* __restrict__ bias,          // bq_l [256]
    const float* __restrict__ beta_l,        // [256]
    float* __restrict__ mloc)                // [T][B][H] fp32 local-scan
{
    constexpr int K = H_;
    __shared__ __align__(16) char smem[98304];          // 96 KiB
    short (*lA)[8] = (short(*)[8])smem;                 // 4096 slots (64KB)
    short (*lB)[8] = (short(*)[8])(smem + 65536);       // 2048 slots (32KB)
    float* scr = (float*)smem;                          // [256][65] (phase 3)

    const int tid = threadIdx.x;
    const int lane = tid & 63, wave = tid >> 6;         // 8 waves
    const int wm = wave >> 1, wn = wave & 1;            // 4m x 2n
    const int l15 = lane & 15, quad = lane >> 4;
    const int c  = blockIdx.x;                          // chunk 0..15
    const int m0 = c * 256;
    const int n0 = blockIdx.y * 64;

    // stage B full-K: [4 sub][64 row][8 oct] = 2048 slots
    #pragma unroll
    for (int j = 0; j < 4; ++j) {
        const int base = (wave * 4 + j) * 64;
        const int s = base + lane;
        const int sub = s >> 9, s2 = s & 511;
        const int row = s2 >> 3;
        const int o = (s2 & 7) ^ (row & 7);
        gl_lds16(Bt + (size_t)(n0 + row) * K + sub * 64 + o * 8, &lB[base][0]);
    }

    floatx4 acc[4][2] = {};

    #pragma unroll
    for (int hk = 0; hk < 2; ++hk) {                    // two 128-k halves
        // stage A half: [2 sub][256 row][8 oct] = 4096 slots
        #pragma unroll
        for (int j = 0; j < 8; ++j) {
            const int base = (wave * 8 + j) * 64;
            const int s = base + lane;
            const int sub = s >> 11, s2 = s & 2047;
            const int row = s2 >> 3;
            const int o = (s2 & 7) ^ (row & 7);
            gl_lds16(A + (size_t)(m0 + row) * K + hk * 128 + sub * 64 + o * 8,
                     &lA[base][0]);
        }
        __syncthreads();                                // half staged

        #pragma unroll
        for (int ktl = 0; ktl < 4; ++ktl) {             // 4 x 32-k steps
            const int sub = ktl >> 1, tt = ktl & 1;
            const int bsub = hk * 2 + sub;
            short8 af[4], bf[2];
            #pragma unroll
            for (int f = 0; f < 4; ++f) {
                const int ra = wm * 64 + f * 16 + l15;
                af[f] = *(const short8*)
                    &lA[sub * 2048 + ra * 8 + ((4 * tt + quad) ^ (ra & 7))][0];
            }
            #pragma unroll
            for (int g = 0; g < 2; ++g) {
                const int rb = wn * 32 + g * 16 + l15;
                bf[g] = *(const short8*)
                    &lB[bsub * 512 + rb * 8 + ((4 * tt + quad) ^ (rb & 7))][0];
            }
            #pragma unroll
            for (int f = 0; f < 4; ++f)
                #pragma unroll
                for (int g = 0; g < 2; ++g)
                    acc[f][g] = __builtin_amdgcn_mfma_f32_16x16x32_bf16(
                        af[f], bf[g], acc[f][g], 0, 0, 0);
        }
        __syncthreads();                                // reads done (reuse lA)
    }

    // dump acc + bias to f32 scratch [256][65] (overlaps lA/lB; GEMM done)
    float bv[2];
    #pragma unroll
    for (int g = 0; g < 2; ++g)
        bv[g] = bias[n0 + wn * 32 + g * 16 + l15];
    #pragma unroll
    for (int f = 0; f < 4; ++f)
        #pragma unroll
        for (int g = 0; g < 2; ++g)
            #pragma unroll
            for (int r = 0; r < 4; ++r)
                scr[(wm * 64 + f * 16 + quad * 4 + r) * 65 +
                    wn * 32 + g * 16 + l15] = acc[f][g][r] + bv[g];
    __syncthreads();

    // chunk-local scan over 32 t-steps, write mloc (same math as R6)
    {
        const int b = tid >> 6;                         // 0..7
        const int hl = tid & 63;
        const float bt = beta_l[n0 + hl];
        float mem = 0.0f;
        #pragma unroll
        for (int tt = 0; tt < CH_; ++tt) {
            mem = fmaf(bt, mem, scr[(tt * 8 + b) * 65 + hl]);
            mloc[((size_t)(c * CH_ + tt) * B_ + b) * H_ + n0 + hl] = mem;
        }
    }
}

// ---------------------------------------------------------------------------
// Fused scan-apply + fc GEMM.  Grid (32 m-tiles, 4 n-tiles), 256 thr.
// Block tile: 128 m-rows (half a chunk: 16 t-steps) x 64 n-cols. Phase 1:
// rebuild spikes for its 128 rows x all 256 h from mloc + cross-chunk carry
// (bitwise the R6 scan_apply formula: b32 by 5 squarings, carry fma chain
// ascending, pw by serial multiplies) writing bf16 straight into the
// XOR-swizzled LDS A-tile. Phase 2: fc GEMM from LDS-A + staged WfcT,
// ReLU + f2bf to h_bf.  `spk` never touches global memory.
// ---------------------------------------------------------------------------
__global__ __launch_bounds__(256) void scan_fc_kernel(
    const float* __restrict__ mloc,          // [T][B][H] fp32 local-scan
    const float* __restrict__ beta_l,        // [256]
    const unsigned short* __restrict__ Bt,   // WfcT [256][256] bf16
    const float* __restrict__ bias,          // bfc_l [256]
    unsigned short* __restrict__ Cb)         // h_bf out [M][256] bf16
{
    constexpr int K = H_, N = H_;
    __shared__ __align__(16) short lA[4096][8];  // 64KB: spk [4 sub][128][8]
    __shared__ __align__(16) short lB[2048][8];  // 32KB: B   [4 sub][64][8]

    const int tid = threadIdx.x;
    const int lane = tid & 63, wave = tid >> 6;  // 4 waves
    const int wm = wave >> 1, wn = wave & 1;     // 2m x 2n of (64m x 32n)
    const int l15 = lane & 15, quad = lane >> 4;
    const int bx = blockIdx.x;                   // 0..31 m-tile
    const int c = bx >> 1, half = bx & 1;        // chunk, chunk-half
    const int m0 = bx * 128;
    const int n0 = blockIdx.y * 64;
    const int tw = c * CH_ + half * 16;          // first t of this tile

    // issue B staging first -> HBM/L2 latency hides under phase 1
    #pragma unroll
    for (int j = 0; j < 8; ++j) {
        const int base = (wave * 8 + j) * 64;
        const int s = base + lane;
        const int sub = s >> 9, s2 = s & 511;
        const int row = s2 >> 3;
        const int o = (s2 & 7) ^ (row & 7);
        gl_lds16(Bt + (size_t)(n0 + row) * K + sub * 64 + o * 8, &lB[base][0]);
    }

    // phase 1: spikes for 128 rows x 256 h -> swizzled LDS A-tile
    {
        const int b  = tid >> 5;                 // 0..7
        const int h5 = tid & 31;
        unsigned short* lAu = (unsigned short*)lA;
        #pragma unroll
        for (int q = 0; q < 8; ++q) {
            const int h = q * 32 + h5;
            const float bt = beta_l[h];
            float b32 = bt;
            #pragma unroll
            for (int i = 0; i < 5; ++i) b32 *= b32;          // beta^32
            float carry = 0.0f;
            for (int j = 0; j < c; ++j)                      // cross-chunk
                carry = fmaf(b32, carry,
                             mloc[((size_t)(j * CH_ + CH_ - 1) * B_ + b) * H_ + h]);
            float pw = bt;                                   // beta^(tt+1)
            for (int i = 0; i < half * 16; ++i) pw *= bt;    // serial: bitwise
            const float* mp = mloc + ((size_t)tw * B_ + b) * H_ + h;
            #pragma unroll
            for (int tt = 0; tt < 16; ++tt) {
                const float mem = fmaf(pw, carry, mp[(size_t)tt * (B_ * H_)]);
                pw *= bt;
                const unsigned short sv =
                    (mem > 1.0f) ? (unsigned short)0x3F80u : (unsigned short)0u;
                const int row = tt * 8 + b;                  // m-local
                const int sub = h >> 6, kk = h & 63;
                const int o = (kk >> 3) ^ (row & 7);
                lAu[(size_t)(sub * 1024 + row * 8 + o) * 8 + (kk & 7)] = sv;
            }
        }
    }
    __syncthreads();   // drains ds_writes (lgkm) AND B gl_lds (vm)

    // phase 2: fc GEMM entirely from LDS
    floatx4 acc[4][2] = {};
    #pragma unroll
    for (int kt = 0; kt < 8; ++kt) {                 // ascending 32-k steps
        const int sub = kt >> 1, tt = kt & 1;
        short8 af[4], bf[2];
        #pragma unroll
        for (int f = 0; f < 4; ++f) {
            const int ra = wm * 64 + f * 16 + l15;
            af[f] = *(const short8*)
                &lA[sub * 1024 + ra * 8 + ((4 * tt + quad) ^ (ra & 7))][0];
        }
        #pragma unroll
        for (int g = 0; g < 2; ++g) {
            const int rb = wn * 32 + g * 16 + l15;
            bf[g] = *(const short8*)
                &lB[sub * 512 + rb * 8 + ((4 * tt + quad) ^ (rb & 7))][0];
        }
        #pragma unroll
        for (int f = 0; f < 4; ++f)
            #pragma unroll
            for (int g = 0; g < 2; ++g)
                acc[f][g] = __builtin_amdgcn_mfma_f32_16x16x32_bf16(
                    af[f], bf[g], acc[f][g], 0, 0, 0);
    }

    #pragma unroll
    for (int g = 0; g < 2; ++g) {
        const int col = n0 + wn * 32 + g * 16 + l15;
        const float bv = bias[col];
        #pragma unroll
        for (int f = 0; f < 4; ++f) {
            const int rbase = m0 + wm * 64 + f * 16 + quad * 4;
            #pragma unroll
            for (int r = 0; r < 4; ++r) {
                const float v = fmaxf(acc[f][g][r] + bv, 0.0f);
                Cb[(size_t)(rbase + r) * N + col] = f2bf(v);
            }
        }
    }
}

// ---------------------------------------------------------------------------
// Final projection: C[M,V] = A[M,256]bf16 @ WoutT[V,256]^T + bias, fp32 out.
// BK=32 double-buffered 2-phase K-pipeline; epilogue = per-wave LDS scratch
// -> full-line (4 rows x 256 B) NON-TEMPORAL stores. R7 proved NT is
// load-bearing: plain stores through L2 cost +150us on the 524 MB C stream.
// Do not remove NT.
// ---------------------------------------------------------------------------
__global__ __launch_bounds__(256, 2) void gemm_mfma_out(
    const unsigned short* __restrict__ A,    // [M][256] bf16
    const unsigned short* __restrict__ Bt,   // [V][256] bf16
    const float* __restrict__ bias,          // [V]
    float* __restrict__ C)
{
    constexpr int K = H_, N = V_;
    __shared__ __align__(16) short lA[2][1024][8];  // 2 x 16 KiB
    __shared__ __align__(16) short lB[2][512][8];   // 2 x  8 KiB

    const int tid = threadIdx.x;
    const int lane = tid & 63, wave = tid >> 6;
    const int wm = wave >> 1, wn = wave & 1;     // wave-tile: 128m x 64n
    const int l15 = lane & 15, quad = lane >> 4;
    const int m0 = blockIdx.x * 256;             // x = m (fast)
    const int n0 = blockIdx.y * 128;

    floatx4 acc[8][4] = {};

    auto stage = [&](int buf, int ks) {
        const int k0 = ks * 32;
        #pragma unroll
        for (int j = 0; j < 4; ++j) {            // A: 1024 slots
            const int base = (wave * 4 + j) * 64;
            const int s = base + lane;
            const int row = s >> 2;
            const int oct = (s & 3) ^ ((row >> 1) & 3);
            gl_lds16(A + (size_t)(m0 + row) * K + k0 + oct * 8, &lA[buf][base][0]);
        }
        #pragma unroll
        for (int j = 0; j < 2; ++j) {            // B: 512 slots
            const int base = (wave * 2 + j) * 64;
            const int s = base + lane;
            const int row = s >> 2;
            const int oct = (s & 3) ^ ((row >> 1) & 3);
            gl_lds16(Bt + (size_t)(n0 + row) * K + k0 + oct * 8, &lB[buf][base][0]);
        }
    };

    stage(0, 0);
    __syncthreads();                              // buf0 staged (full drain)

    for (int ks = 0; ks < 8; ++ks) {
        const int cur = ks & 1;
        if (ks < 7) stage(cur ^ 1, ks + 1);       // prefetch next slice first
        short8 af[8], bf[4];
        #pragma unroll
        for (int f = 0; f < 8; ++f) {
            const int ra = wm * 128 + f * 16 + l15;
            af[f] = *(const short8*)&lA[cur][ra * 4 + (quad ^ ((ra >> 1) & 3))][0];
        }
        #pragma unroll
        for (int g = 0; g < 4; ++g) {
            const int rb = wn * 64 + g * 16 + l15;
            bf[g] = *(const short8*)&lB[cur][rb * 4 + (quad ^ ((rb >> 1) & 3))][0];
        }
        #pragma unroll
        for (int f = 0; f < 8; ++f)
            #pragma unroll
            for (int g = 0; g < 4; ++g)
                acc[f][g] = __builtin_amdgcn_mfma_f32_16x16x32_bf16(
                    af[f], bf[g], acc[f][g], 0, 0, 0);
        __syncthreads();
    }

    // ---- epilogue via per-wave LDS scratch -> full-line NT stores ----
    // D layout per frag: col(n) = l15, row(m) = quad*4 + r (m89/m91-verified).
    float* scr = (float*)&lA[0][0][0] + (size_t)wave * 1088;   // 16 x 68 fp32
    float bvv[4];
    #pragma unroll
    for (int g = 0; g < 4; ++g)
        bvv[g] = bias[n0 + wn * 64 + g * 16 + l15];

    #pragma unroll
    for (int f = 0; f < 8; ++f) {
        #pragma unroll
        for (int g = 0; g < 4; ++g)
            #pragma unroll
            for (int r = 0; r < 4; ++r)
                scr[(quad * 4 + r) * 68 + g * 16 + l15] = acc[f][g][r] + bvv[g];
        asm volatile("s_waitcnt lgkmcnt(0)" ::: "memory");
        #pragma unroll
        for (int rr = 0; rr < 4; ++rr) {
            const int ml = rr * 4 + quad;
            const floatx4 v = *(const floatx4*)&scr[ml * 68 + l15 * 4];
            const size_t m = (size_t)(m0 + wm * 128 + f * 16 + ml);
            __builtin_nontemporal_store(
                v, (floatx4*)&C[m * (size_t)N + n0 + wn * 64 + l15 * 4]);
        }
        asm volatile("s_waitcnt lgkmcnt(0)" ::: "memory");  // reads landed
    }
}

// ---------------------------------------------------------------------------
extern "C" void kernel_launch(void* const* d_in, const int* in_sizes, int n_in,
                              void* d_out, int out_size, void* d_ws, size_t ws_size,
                              hipStream_t stream)
{
    const int*   tokens = (const int*)  d_in[0];
    const float* temb   = (const float*)d_in[1];
    const float* pemb   = (const float*)d_in[2];
    const float* Wq     = (const float*)d_in[3];
    const float* bq     = (const float*)d_in[4];
    const float* beta   = (const float*)d_in[5];
    const float* Wfc    = (const float*)d_in[6];
    const float* bfc    = (const float*)d_in[7];
    const float* Wout   = (const float*)d_in[8];
    const float* bout   = (const float*)d_in[9];
    float* out = (float*)d_out;

    // Workspace layout (16B-aligned): h_bf 2MB | WT 0.75MB | WoutT 16MB |
    // mloc 4MB.  (cur and spk eliminated by the per-layer fusion.)
    unsigned short* h_bf  = (unsigned short*)d_ws;
    unsigned short* WT    = h_bf + (size_t)M_ * H_;         // 6 x [256][256]
    unsigned short* WoutT = WT + (size_t)2 * L_ * H_ * H_;
    float*          mloc  = (float*)(WoutT + (size_t)V_ * H_);

    // Weight transposes (independent of activation pipeline) — one dispatch
    transpose_all_kernel<<<96 + (V_ / 64) * (H_ / 64), 256, 0, stream>>>(
        Wq, Wfc, Wout, WT, WoutT);

    // 1) embed (bf16 activations)
    embed_kernel<<<(M_ * H_ / 4) / 256, 256, 0, stream>>>(tokens, temb, pemb, h_bf);

    // 2) layers: fused (qproj + local scan) -> fused (scan-apply + fc)
    for (int l = 0; l < L_; ++l) {
        const unsigned short* WqT  = WT + (size_t)l * H_ * H_;
        const unsigned short* WfcT = WT + (size_t)(L_ + l) * H_ * H_;
        qproj_scan_kernel<<<dim3(NT_, 4), 512, 0, stream>>>(
            h_bf, WqT, bq + (size_t)l * H_, beta + (size_t)l * H_, mloc);
        scan_fc_kernel<<<dim3(M_ / 128, 4), 256, 0, stream>>>(
            mloc, beta + (size_t)l * H_, WfcT, bfc + (size_t)l * H_, h_bf);
    }

    // 3) output projection: (4096 x 256) @ (256 x 32000) + bout
    gemm_mfma_out<<<dim3(M_ / 256, V_ / 128), 256, 0, stream>>>(
        h_bf, WoutT, bout, out);
}